// Round 1
// baseline (83.148 us; speedup 1.0000x reference)
//
#include <hip/hip_runtime.h>

namespace {
constexpr int kB = 8;
constexpr int kC = 1025;
constexpr int kT = 3000;
constexpr int kBlock = 256;
constexpr int kChunk = 12;                 // 250 threads * 12 = 3000
constexpr int kActiveScan = kT / kChunk;   // 250
constexpr float kPi = 3.14159265358979323846f;     // rounds to 0x40490FDB == np.float32(np.pi)
constexpr float kTwoPi = 6.28318530717958647692f;
}  // namespace

__global__ __launch_bounds__(kBlock) void coherent_polar_kernel(
    const float* __restrict__ xr, const float* __restrict__ xi,
    float* __restrict__ out) {
  __shared__ float s_ph[kT];     // 12 KB: per-row phases
  __shared__ float s_wsum[4];
  __shared__ float s_wmin[4];
  __shared__ float s_wmax[4];

  const int row = blockIdx.x;            // [0, B*C)
  const int b = row / kC;
  const int c = row - b * kC;
  const float* re = xr + (size_t)row * kT;
  const float* im = xi + (size_t)row * kT;
  float* mag_out = out + ((size_t)b * (2 * kC) + c) * kT;
  float* ph_out  = out + ((size_t)b * (2 * kC) + kC + c) * kT;

  const int tid = threadIdx.x;
  const int lane = tid & 63;
  const int wave = tid >> 6;

  // ---- Pass 1: coalesced float4 loads; magnitude -> global, phase -> LDS ----
  // kT % 4 == 0 and row bases are 16B-aligned (kT*4 = 12000 = 750*16), so
  // every float4 is aligned and fully in-range (base=3000.. is fully out).
#pragma unroll
  for (int s = 0; s < 3; ++s) {
    const int base = s * (kBlock * 4) + tid * 4;
    if (base < kT) {
      const float4 r4 = *reinterpret_cast<const float4*>(re + base);
      const float4 i4 = *reinterpret_cast<const float4*>(im + base);
      float4 m4;
      m4.x = sqrtf(r4.x * r4.x + i4.x * i4.x);
      m4.y = sqrtf(r4.y * r4.y + i4.y * i4.y);
      m4.z = sqrtf(r4.z * r4.z + i4.z * i4.z);
      m4.w = sqrtf(r4.w * r4.w + i4.w * i4.w);
      *reinterpret_cast<float4*>(mag_out + base) = m4;
      float4 p4;
      p4.x = atan2f(i4.x, r4.x);
      p4.y = atan2f(i4.y, r4.y);
      p4.z = atan2f(i4.z, r4.z);
      p4.w = atan2f(i4.w, r4.w);
      *reinterpret_cast<float4*>(&s_ph[base]) = p4;
    }
  }
  __syncthreads();

  // ---- Pass 2: segmented unwrap-scan. Thread t owns elements [12t, 12t+12).
  const int a = tid * kChunk;
  const bool active = tid < kActiveScan;

  float phv[kChunk];
  float run = 0.0f;
  if (active) {
    float p = (a > 0) ? s_ph[a - 1] : s_ph[0];   // a==0: step at t=0 is 0
#pragma unroll
    for (int k = 0; k < kChunk; ++k) {
      const float cur = s_ph[a + k];
      const float d = cur - p;
      p = cur;
      float step = 0.0f;
      if (d < -kPi) step = kTwoPi;
      else if (d > kPi) step = -kTwoPi;
      run += step;
      phv[k] = cur + run;                        // phase + local step-prefix
    }
  }
  const float total = active ? run : 0.0f;

  // wave-level inclusive scan of per-thread step totals
  float inc = total;
#pragma unroll
  for (int d = 1; d < 64; d <<= 1) {
    const float n = __shfl_up(inc, d);
    if (lane >= d) inc += n;
  }
  const float excl = inc - total;
  if (lane == 63) s_wsum[wave] = inc;
  __syncthreads();
  float wave_prefix = 0.0f;
#pragma unroll
  for (int w = 0; w < 3; ++w)
    if (w < wave) wave_prefix += s_wsum[w];
  const float E = wave_prefix + excl;            // correction base for this chunk

  // unwrapped min/max
  float mn = __builtin_inff();
  float mx = -__builtin_inff();
  if (active) {
#pragma unroll
    for (int k = 0; k < kChunk; ++k) {
      const float u = phv[k] + E;
      mn = fminf(mn, u);
      mx = fmaxf(mx, u);
    }
  }
#pragma unroll
  for (int m = 32; m >= 1; m >>= 1) {
    mn = fminf(mn, __shfl_xor(mn, m));
    mx = fmaxf(mx, __shfl_xor(mx, m));
  }
  if (lane == 0) { s_wmin[wave] = mn; s_wmax[wave] = mx; }
  __syncthreads();
  mn = fminf(fminf(s_wmin[0], s_wmin[1]), fminf(s_wmin[2], s_wmin[3]));
  mx = fmaxf(fmaxf(s_wmax[0], s_wmax[1]), fmaxf(s_wmax[2], s_wmax[3]));
  const float inv = 1.0f / (mx - mn + 1e-8f);

  // normalized phase out: 3 aligned float4 stores per active thread
  if (active) {
#pragma unroll
    for (int k = 0; k < kChunk; k += 4) {
      float4 o;
      o.x = (phv[k + 0] + E - mn) * inv;
      o.y = (phv[k + 1] + E - mn) * inv;
      o.z = (phv[k + 2] + E - mn) * inv;
      o.w = (phv[k + 3] + E - mn) * inv;
      *reinterpret_cast<float4*>(ph_out + a + k) = o;
    }
  }
}

extern "C" void kernel_launch(void* const* d_in, const int* in_sizes, int n_in,
                              void* d_out, int out_size, void* d_ws, size_t ws_size,
                              hipStream_t stream) {
  const float* xr = (const float*)d_in[0];
  const float* xi = (const float*)d_in[1];
  float* out = (float*)d_out;
  coherent_polar_kernel<<<dim3(kB * kC), dim3(kBlock), 0, stream>>>(xr, xi, out);
}